// Round 7
// baseline (265.682 us; speedup 1.0000x reference)
//
#include <hip/hip_runtime.h>

typedef __attribute__((ext_vector_type(2))) float f32x2;

#define W 4096
#define H 4096
#define NT 256
#define COLS 512                 // columns per block (2 per thread)
#define SR 16                    // output rows per block strip (was 32)
#define GROUP 4                  // rows staged per barrier
#define NSTAGE (SR + 14)         // 30 staged rows contribute
#define NG 8                     // 8 groups of 4 (32 slots, last 2 guarded off)
#define LW (COLS + 16)           // 528 floats per staged row (8-col halo each side)
#define NCHUNK (LW / 4)          // 132 float4 chunks per row
#define RAD 7
#define PEND 18                  // 15 + GROUP - 1

__global__ __launch_bounds__(NT, 4) void multibox_kernel(
    const float* __restrict__ x, const float* __restrict__ base,
    float* __restrict__ out)
{
    __shared__ float buf[2][GROUP][LW];   // 16,896 B -> 8 blocks/CU fits 160 KiB

    const int t  = threadIdx.x;
    const int c0 = blockIdx.x * COLS;
    const int i0 = blockIdx.y * SR;

    const float w3  = 1.f/(7.f*9.f);
    const float w5  = 1.f/(7.f*25.f);
    const float w7  = 1.f/(7.f*49.f);
    const float w9  = 1.f/(7.f*81.f);
    const float w11 = 1.f/(7.f*121.f);
    const float w13 = 1.f/(7.f*169.f);
    const float w15 = 1.f/(7.f*225.f);

    auto ld4 = [&](const float* __restrict__ rowp, int c) -> float4 {
        if (c >= 0 && c <= W - 4) return *(const float4*)(rowp + c);
        float4 v;
        v.x = rowp[min(max(c    , 0), W - 1)];
        v.y = rowp[min(max(c + 1, 0), W - 1)];
        v.z = rowp[min(max(c + 2, 0), W - 1)];
        v.w = rowp[min(max(c + 3, 0), W - 1)];
        return v;
    };

    float4 mreg[GROUP];

    auto load_group = [&](int g) {
        if (t < NCHUNK) {
            const int rb = i0 - RAD + g * GROUP;
#pragma unroll
            for (int rr = 0; rr < GROUP; ++rr) {
                const int rc = min(max(rb + rr, 0), H - 1);
                mreg[rr] = ld4(x + (size_t)rc * W, c0 - 8 + 4 * t);
            }
        }
    };

    auto write_group = [&](int b) {
        if (t < NCHUNK) {
#pragma unroll
            for (int rr = 0; rr < GROUP; ++rr)
                *(float4*)&buf[b][rr][4 * t] = mreg[rr];
        }
    };

    // Pnd[p] accumulates output row (i0 + 4g - 14 + p) before group g.
    // rr / p are compile-time (inner unrolls); g stays RUNTIME -> no
    // scratch demotion (round-4 lesson), demand stays within 64 VGPRs.
    f32x2 Pnd[PEND];
#pragma unroll
    for (int q = 0; q < PEND; ++q) Pnd[q] = f32x2{0.f, 0.f};

    auto compute_group = [&](int b, int g) {
#pragma unroll
        for (int rr = 0; rr < GROUP; ++rr) {
            if (g * GROUP + rr < NSTAGE) {
                const float* p = &buf[b][rr][2 * t];
                f32x2 q2[9];
#pragma unroll
                for (int i = 0; i < 9; ++i) q2[i] = *(const f32x2*)(p + 2 * i);

                auto PR = [&](int a) -> f32x2 {
                    if ((a & 1) == 0) return q2[a / 2];
                    f32x2 r;
                    r.x = q2[a / 2].y;
                    r.y = q2[a / 2 + 1].x;
                    return r;
                };

                f32x2 s3  = PR(7) + PR(8) + PR(9);
                f32x2 s5  = s3  + PR(6) + PR(10);
                f32x2 s7  = s5  + PR(5) + PR(11);
                f32x2 s9  = s7  + PR(4) + PR(12);
                f32x2 s11 = s9  + PR(3) + PR(13);
                f32x2 s13 = s11 + PR(2) + PR(14);
                f32x2 s15 = s13 + PR(1) + PR(15);

                f32x2 c7 = f32x2{w15, w15} * s15;
                f32x2 c6 = c7 + f32x2{w13, w13} * s13;
                f32x2 c5 = c6 + f32x2{w11, w11} * s11;
                f32x2 c4 = c5 + f32x2{w9 , w9 } * s9;
                f32x2 c3 = c4 + f32x2{w7 , w7 } * s7;
                f32x2 c2 = c3 + f32x2{w5 , w5 } * s5;
                f32x2 c1 = c2 + f32x2{w3 , w3 } * s3;

                Pnd[rr +  0] += c7; Pnd[rr +  1] += c6; Pnd[rr +  2] += c5;
                Pnd[rr +  3] += c4; Pnd[rr +  4] += c3; Pnd[rr +  5] += c2;
                Pnd[rr +  6] += c1; Pnd[rr +  7] += c1; Pnd[rr +  8] += c1;
                Pnd[rr +  9] += c2; Pnd[rr + 10] += c3; Pnd[rr + 11] += c4;
                Pnd[rr + 12] += c5; Pnd[rr + 13] += c6; Pnd[rr + 14] += c7;
            }
        }

        // emit the completed output rows: o_ofs = 4g - 14 + p
#pragma unroll
        for (int p = 0; p < GROUP; ++p) {
            const int o_ofs = 4 * g - 14 + p;
            if (o_ofs >= 0 && o_ofs < SR) {
                const size_t bi = (size_t)(i0 + o_ofs) * W + c0 + 2 * t;
                f32x2 bm = *(const f32x2*)(base + bi);
                f32x2 ov = Pnd[p] * bm;
                *(f32x2*)(out + bi) = ov;
            }
        }

        // shift window by GROUP (static indices)
#pragma unroll
        for (int p = 0; p < PEND - GROUP; ++p) Pnd[p] = Pnd[p + GROUP];
#pragma unroll
        for (int p = PEND - GROUP; p < PEND; ++p) Pnd[p] = f32x2{0.f, 0.f};
    };

    load_group(0);
    write_group(0);
    __syncthreads();

    for (int g = 0; g < NG - 1; ++g) {          // runtime loop
        load_group(g + 1);           // issue next group's global loads early
        compute_group(g & 1, g);     // compute current group (hides latency)
        write_group((g + 1) & 1);    // land prefetched rows
        __syncthreads();
    }
    compute_group((NG - 1) & 1, NG - 1);
}

extern "C" void kernel_launch(void* const* d_in, const int* in_sizes, int n_in,
                              void* d_out, int out_size, void* d_ws, size_t ws_size,
                              hipStream_t stream) {
    const float* x    = (const float*)d_in[0];
    const float* base = (const float*)d_in[1];
    float* out        = (float*)d_out;

    dim3 grid(W / COLS, H / SR);   // (8, 256) = 2048 blocks -> 8 blocks/CU
    multibox_kernel<<<grid, dim3(NT), 0, stream>>>(x, base, out);
}

// Round 8
// 70.924 us; speedup vs baseline: 3.7460x; 3.7460x over previous
//
#include <hip/hip_runtime.h>

typedef __attribute__((ext_vector_type(2))) float f32x2;

#define W 4096
#define H 4096
#define NT 256
#define COLS 512                 // columns per block (2 per thread)
#define SR 16                    // output rows per block strip
#define GROUP 4                  // rows staged per barrier
#define NSTAGE (SR + 14)         // 30 staged rows contribute
#define NG 8                     // 8 groups of 4 (32 slots, last 2 guarded off)
#define LW (COLS + 16)           // 528 floats per staged row (8-col halo each side)
#define NCHUNK (LW / 4)          // 132 float4 chunks per row
#define RAD 7
#define PEND 18                  // 15 + GROUP - 1

__global__ __launch_bounds__(NT, 4) void multibox_kernel(
    const float* __restrict__ x, const float* __restrict__ base,
    float* __restrict__ out)
{
    __shared__ float buf[2][GROUP][LW];   // 16,896 B -> 8 blocks/CU fits 160 KiB

    const int t  = threadIdx.x;
    const int c0 = blockIdx.x * COLS;
    const int i0 = blockIdx.y * SR;

    const float w3  = 1.f/(7.f*9.f);
    const float w5  = 1.f/(7.f*25.f);
    const float w7  = 1.f/(7.f*49.f);
    const float w9  = 1.f/(7.f*81.f);
    const float w11 = 1.f/(7.f*121.f);
    const float w13 = 1.f/(7.f*169.f);
    const float w15 = 1.f/(7.f*225.f);

    auto ld4 = [&](const float* __restrict__ rowp, int c) -> float4 {
        if (c >= 0 && c <= W - 4) return *(const float4*)(rowp + c);
        float4 v;
        v.x = rowp[min(max(c    , 0), W - 1)];
        v.y = rowp[min(max(c + 1, 0), W - 1)];
        v.z = rowp[min(max(c + 2, 0), W - 1)];
        v.w = rowp[min(max(c + 3, 0), W - 1)];
        return v;
    };

    float4 mreg[GROUP];

    auto load_group = [&](int g) {
        if (t < NCHUNK) {
            const int rb = i0 - RAD + g * GROUP;
#pragma unroll
            for (int rr = 0; rr < GROUP; ++rr) {
                const int rc = min(max(rb + rr, 0), H - 1);
                mreg[rr] = ld4(x + (size_t)rc * W, c0 - 8 + 4 * t);
            }
        }
    };

    auto write_group = [&](int b) {
        if (t < NCHUNK) {
#pragma unroll
            for (int rr = 0; rr < GROUP; ++rr)
                *(float4*)&buf[b][rr][4 * t] = mreg[rr];
        }
    };

    // Pnd[p] accumulates output row (i0 + 4g - 14 + p) before group g.
    // rr / p are compile-time (inner unrolls); g stays RUNTIME -> no
    // scratch demotion (round-4 lesson), demand stays within 64 VGPRs.
    f32x2 Pnd[PEND];
#pragma unroll
    for (int q = 0; q < PEND; ++q) Pnd[q] = f32x2{0.f, 0.f};

    auto compute_group = [&](int b, int g) {
#pragma unroll
        for (int rr = 0; rr < GROUP; ++rr) {
            if (g * GROUP + rr < NSTAGE) {
                const float* p = &buf[b][rr][2 * t];
                f32x2 q2[9];
#pragma unroll
                for (int i = 0; i < 9; ++i) q2[i] = *(const f32x2*)(p + 2 * i);

                auto PR = [&](int a) -> f32x2 {
                    if ((a & 1) == 0) return q2[a / 2];
                    f32x2 r;
                    r.x = q2[a / 2].y;
                    r.y = q2[a / 2 + 1].x;
                    return r;
                };

                f32x2 s3  = PR(7) + PR(8) + PR(9);
                f32x2 s5  = s3  + PR(6) + PR(10);
                f32x2 s7  = s5  + PR(5) + PR(11);
                f32x2 s9  = s7  + PR(4) + PR(12);
                f32x2 s11 = s9  + PR(3) + PR(13);
                f32x2 s13 = s11 + PR(2) + PR(14);
                f32x2 s15 = s13 + PR(1) + PR(15);

                f32x2 c7 = f32x2{w15, w15} * s15;
                f32x2 c6 = c7 + f32x2{w13, w13} * s13;
                f32x2 c5 = c6 + f32x2{w11, w11} * s11;
                f32x2 c4 = c5 + f32x2{w9 , w9 } * s9;
                f32x2 c3 = c4 + f32x2{w7 , w7 } * s7;
                f32x2 c2 = c3 + f32x2{w5 , w5 } * s5;
                f32x2 c1 = c2 + f32x2{w3 , w3 } * s3;

                Pnd[rr +  0] += c7; Pnd[rr +  1] += c6; Pnd[rr +  2] += c5;
                Pnd[rr +  3] += c4; Pnd[rr +  4] += c3; Pnd[rr +  5] += c2;
                Pnd[rr +  6] += c1; Pnd[rr +  7] += c1; Pnd[rr +  8] += c1;
                Pnd[rr +  9] += c2; Pnd[rr + 10] += c3; Pnd[rr + 11] += c4;
                Pnd[rr + 12] += c5; Pnd[rr + 13] += c6; Pnd[rr + 14] += c7;
            }
        }

        // emit the completed output rows: o_ofs = 4g - 14 + p
#pragma unroll
        for (int p = 0; p < GROUP; ++p) {
            const int o_ofs = 4 * g - 14 + p;
            if (o_ofs >= 0 && o_ofs < SR) {
                const size_t bi = (size_t)(i0 + o_ofs) * W + c0 + 2 * t;
                f32x2 bm = *(const f32x2*)(base + bi);
                f32x2 ov = Pnd[p] * bm;
                *(f32x2*)(out + bi) = ov;
            }
        }

        // shift window by GROUP (static indices)
#pragma unroll
        for (int p = 0; p < PEND - GROUP; ++p) Pnd[p] = Pnd[p + GROUP];
#pragma unroll
        for (int p = PEND - GROUP; p < PEND; ++p) Pnd[p] = f32x2{0.f, 0.f};
    };

    load_group(0);
    write_group(0);
    __syncthreads();

    // MUST stay rolled: full unroll at NG=8 hoists multiple groups' loads,
    // blowing past the 64-VGPR cap (8 waves/SIMD) -> scratch spill (round 7).
#pragma clang loop unroll(disable)
    for (int g = 0; g < NG - 1; ++g) {
        load_group(g + 1);           // issue next group's global loads early
        compute_group(g & 1, g);     // compute current group (hides latency)
        write_group((g + 1) & 1);    // land prefetched rows
        __syncthreads();
    }
    compute_group((NG - 1) & 1, NG - 1);
}

extern "C" void kernel_launch(void* const* d_in, const int* in_sizes, int n_in,
                              void* d_out, int out_size, void* d_ws, size_t ws_size,
                              hipStream_t stream) {
    const float* x    = (const float*)d_in[0];
    const float* base = (const float*)d_in[1];
    float* out        = (float*)d_out;

    dim3 grid(W / COLS, H / SR);   // (8, 256) = 2048 blocks -> 8 blocks/CU
    multibox_kernel<<<grid, dim3(NT), 0, stream>>>(x, base, out);
}

// Round 9
// 45.911 us; speedup vs baseline: 5.7869x; 1.5448x over previous
//
#include <hip/hip_runtime.h>

typedef __attribute__((ext_vector_type(2))) float f32x2;

#define W 4096
#define H 4096
#define NT 256
#define NW 4
#define COLS 512                 // columns per block (2 per thread)
#define SR 32                    // output rows per block strip
#define GROUP 4                  // rows staged per barrier (1 per wave, DMA)
#define NSTAGE (SR + 14)         // 46 staged rows contribute
#define NG 12                    // 12 groups of 4
#define LW 576                   // padded staged row: 2*256 + 64 floats (DMA-linear)
#define RAD 7
#define PEND 18                  // 15 + GROUP - 1

__device__ __forceinline__ void gl_lds16(float* lds, const float* g) {
    __builtin_amdgcn_global_load_lds(
        (const __attribute__((address_space(1))) void*)g,
        (__attribute__((address_space(3))) void*)lds, 16, 0, 0);
}
__device__ __forceinline__ void gl_lds4(float* lds, const float* g) {
    __builtin_amdgcn_global_load_lds(
        (const __attribute__((address_space(1))) void*)g,
        (__attribute__((address_space(3))) void*)lds, 4, 0, 0);
}

__global__ __launch_bounds__(NT, 4) void multibox_kernel(
    const float* __restrict__ x, const float* __restrict__ base,
    float* __restrict__ out)
{
    __shared__ float buf[2][GROUP][LW];   // 18,432 B

    const int t  = threadIdx.x;
    const int w  = t >> 6;                // wave id: stages row w of each group
    const int l  = t & 63;                // lane
    const int c0 = blockIdx.x * COLS;
    const int i0 = blockIdx.y * SR;

    const float w3  = 1.f/(7.f*9.f);
    const float w5  = 1.f/(7.f*25.f);
    const float w7  = 1.f/(7.f*49.f);
    const float w9  = 1.f/(7.f*81.f);
    const float w11 = 1.f/(7.f*121.f);
    const float w13 = 1.f/(7.f*169.f);
    const float w15 = 1.f/(7.f*225.f);

    // per-lane DMA source columns (invariant across groups).
    // op0/op1: 16B ops, lane l covers floats [256i+4l .. +3]; chunk-base clamp
    // is exact except block 0's floats 0..7 (patched below).
    // op2: 4B op, 1 float/lane -> per-lane clamp IS exact edge replication.
    const int colA = min(max(c0 -   8 + 4 * l, 0), W - 4);
    const int colB =         c0 + 248 + 4 * l;             // always in-range
    const int colC = min(    c0 + 504 +     l,     W - 1); // right-edge exact

    // each wave DMAs its one row of group g into slot b: 3 instructions
    auto stage = [&](int g, int b) {
        const int rc = min(max(i0 - RAD + g * GROUP + w, 0), H - 1);
        const float* rp = x + (size_t)rc * W;
        gl_lds16(&buf[b][w][0],   rp + colA);
        gl_lds16(&buf[b][w][256], rp + colB);
        gl_lds4 (&buf[b][w][512], rp + colC);
    };

    // block x==0 only: left-edge floats 0..7 := x[row][0] (already at idx 8)
    auto patch = [&](int b) {
        if (l < 8) buf[b][w][l] = buf[b][w][8];
    };

    // Pnd[p] accumulates output row (i0 + 4g - 14 + p) before group g.
    // rr / p compile-time (inner unrolls); g stays RUNTIME (rounds 4/7 lesson).
    f32x2 Pnd[PEND];
#pragma unroll
    for (int q = 0; q < PEND; ++q) Pnd[q] = f32x2{0.f, 0.f};

    auto compute_group = [&](int b, int g) {
#pragma unroll
        for (int rr = 0; rr < GROUP; ++rr) {
            if (g * GROUP + rr < NSTAGE) {
                const float* p = &buf[b][rr][2 * t];
                f32x2 q2[9];
#pragma unroll
                for (int i = 0; i < 9; ++i) q2[i] = *(const f32x2*)(p + 2 * i);

                auto PR = [&](int a) -> f32x2 {
                    if ((a & 1) == 0) return q2[a / 2];
                    f32x2 r;
                    r.x = q2[a / 2].y;
                    r.y = q2[a / 2 + 1].x;
                    return r;
                };

                f32x2 s3  = PR(7) + PR(8) + PR(9);
                f32x2 s5  = s3  + PR(6) + PR(10);
                f32x2 s7  = s5  + PR(5) + PR(11);
                f32x2 s9  = s7  + PR(4) + PR(12);
                f32x2 s11 = s9  + PR(3) + PR(13);
                f32x2 s13 = s11 + PR(2) + PR(14);
                f32x2 s15 = s13 + PR(1) + PR(15);

                f32x2 c7 = f32x2{w15, w15} * s15;
                f32x2 c6 = c7 + f32x2{w13, w13} * s13;
                f32x2 c5 = c6 + f32x2{w11, w11} * s11;
                f32x2 c4 = c5 + f32x2{w9 , w9 } * s9;
                f32x2 c3 = c4 + f32x2{w7 , w7 } * s7;
                f32x2 c2 = c3 + f32x2{w5 , w5 } * s5;
                f32x2 c1 = c2 + f32x2{w3 , w3 } * s3;

                Pnd[rr +  0] += c7; Pnd[rr +  1] += c6; Pnd[rr +  2] += c5;
                Pnd[rr +  3] += c4; Pnd[rr +  4] += c3; Pnd[rr +  5] += c2;
                Pnd[rr +  6] += c1; Pnd[rr +  7] += c1; Pnd[rr +  8] += c1;
                Pnd[rr +  9] += c2; Pnd[rr + 10] += c3; Pnd[rr + 11] += c4;
                Pnd[rr + 12] += c5; Pnd[rr + 13] += c6; Pnd[rr + 14] += c7;
            }
        }

        // emit the completed output rows: o_ofs = 4g - 14 + p
#pragma unroll
        for (int p = 0; p < GROUP; ++p) {
            const int o_ofs = 4 * g - 14 + p;
            if (o_ofs >= 0 && o_ofs < SR) {
                const size_t bi = (size_t)(i0 + o_ofs) * W + c0 + 2 * t;
                f32x2 bm = *(const f32x2*)(base + bi);
                f32x2 ov = Pnd[p] * bm;
                *(f32x2*)(out + bi) = ov;
            }
        }

        // shift window by GROUP (static indices)
#pragma unroll
        for (int p = 0; p < PEND - GROUP; ++p) Pnd[p] = Pnd[p + GROUP];
#pragma unroll
        for (int p = PEND - GROUP; p < PEND; ++p) Pnd[p] = f32x2{0.f, 0.f};
    };

    stage(0, 0);
    __syncthreads();                       // drains DMA (vmcnt) + orders LDS
    if (c0 == 0) { patch(0); __syncthreads(); }   // workgroup-uniform branch

    // MUST stay rolled (round-7 lesson: unroll hoists loads -> spill)
#pragma clang loop unroll(disable)
    for (int g = 0; g < NG - 1; ++g) {
        stage(g + 1, (g + 1) & 1);   // 3 DMA instrs/wave, issued before compute
        compute_group(g & 1, g);     // ds_read + VALU + emit (hides DMA latency)
        __syncthreads();             // next group's rows landed
        if (c0 == 0) { patch((g + 1) & 1); __syncthreads(); }
    }
    compute_group((NG - 1) & 1, NG - 1);
}

extern "C" void kernel_launch(void* const* d_in, const int* in_sizes, int n_in,
                              void* d_out, int out_size, void* d_ws, size_t ws_size,
                              hipStream_t stream) {
    const float* x    = (const float*)d_in[0];
    const float* base = (const float*)d_in[1];
    float* out        = (float*)d_out;

    dim3 grid(W / COLS, H / SR);   // (8, 128) = 1024 blocks
    multibox_kernel<<<grid, dim3(NT), 0, stream>>>(x, base, out);
}